// Round 1
// baseline (1484.399 us; speedup 1.0000x reference)
//
#include <hip/hip_runtime.h>
#include <stdint.h>

#define R_NODES 256
#define M_SAMP  512
#define S_STEPS 512
#define OUT_N   10

// ---------------- layout detection for bool inputs ----------------
// If bools were uploaded as int32, byte (4f+1) of every element is 0.
// If uploaded as uint8, ~half those bytes are 1.  flag=1 => uint8 layout.
__global__ void detect_layout(const uint8_t* __restrict__ x, int* __restrict__ flag) {
    __shared__ int any;
    if (threadIdx.x == 0) any = 0;
    __syncthreads();
    int acc = 0;
    for (int i = 0; i < 64; ++i)
        acc |= x[(size_t)(threadIdx.x * 64 + i) * 4 + 1];
    if (acc) atomicOr(&any, 1);
    __syncthreads();
    if (threadIdx.x == 0) *flag = any ? 1 : 0;
}

// ---------------- pack x bits: one uint32 per (m,s) ----------------
__global__ void pack_x(const uint8_t* __restrict__ x, const int* __restrict__ flag,
                       uint32_t* __restrict__ xp) {
    const int stride = (*flag) ? 1 : 4;
    const int f = blockIdx.x * blockDim.x + threadIdx.x;      // element idx, M*S*32 total
    const int val = x[(size_t)f * stride];
    const uint64_t mask = __ballot(val != 0);
    const int lane = threadIdx.x & 63;
    if ((lane & 31) == 0) {
        uint32_t w = (lane & 32) ? (uint32_t)(mask >> 32) : (uint32_t)mask;
        xp[f >> 5] = w;
    }
}

// ---------------- build byte-chunk partial-sum table (permuted bits) ----
// T2[(v*32 + c)*256 + j]: bit p of v refers to node column
//     k = c*8 + (p&1)*4 + (p>>1)
// This matches the ballot layout of the wave-per-sample main kernel:
//     u_c = ((b0>>2c)&3) | ((b1>>2c)&3)<<2 | ((b2>>2c)&3)<<4 | ((b3>>2c)&3)<<6
// where b_k = ballot(state of node 4*lane+k); bit (2k+h) of u_c = state of
// node 8c + 4h + k.  Per-chunk max sum ~12.9K (uint16 safe; 4-chunk group
// sums <= 51808, still uint16-field safe for packed adds).
__global__ void build_T2(const uint8_t* __restrict__ wres, const int* __restrict__ primes,
                         const int* __restrict__ flag, uint16_t* __restrict__ T2) {
    const int v = blockIdx.x;          // 0..255 permuted byte value
    const int c = blockIdx.y;          // 0..31 chunk
    const int j = threadIdx.x;         // 0..255 node
    const int stride = (*flag) ? 1 : 4;
    int sum = 0;
#pragma unroll
    for (int p = 0; p < 8; ++p) {
        if ((v >> p) & 1) {
            const int k = c * 8 + ((p & 1) << 2) + (p >> 1);
            if (wres[(size_t)(j * 256 + k) * stride]) sum += primes[k];
        }
    }
    T2[((size_t)v * 32 + c) * 256 + j] = (uint16_t)sum;
}

// ---------------- bit-pack the LUT: 256MB int32 -> 8MB bits ----------------
// Lane-coalesced int4 loads; 4 ballots/iter; lanes 0..7 assemble 8 output
// words via bit-spread. 16384 waves x 16 iters (was 2048x128): enough
// independent waves to hide HBM latency -> BW-bound.
__device__ __forceinline__ uint32_t spread8(uint32_t x) {
    // bit i of low byte -> bit 4*i
    x = (x | (x << 12)) & 0x000F000Fu;
    x = (x | (x << 6))  & 0x03030303u;
    x = (x | (x << 3))  & 0x11111111u;
    return x;
}
__global__ void pack_lut(const int* __restrict__ lut, uint32_t* __restrict__ lp32) {
    const int lane = threadIdx.x & 63;
    const int gw = blockIdx.x * (blockDim.x >> 6) + (threadIdx.x >> 6); // 16384 waves
    const int4* src = (const int4*)lut;
    for (int it = 0; it < 16; ++it) {
        const int chunk = gw * 16 + it;                // 262144 wave-chunks total
        const int4 q = src[(size_t)chunk * 64 + lane]; // coalesced 16B/lane
        const uint64_t b0 = __ballot((q.x & 1) != 0);
        const uint64_t b1 = __ballot((q.y & 1) != 0);
        const uint64_t b2 = __ballot((q.z & 1) != 0);
        const uint64_t b3 = __ballot((q.w & 1) != 0);
        if (lane < 8) {
            const uint32_t B0 = (uint32_t)(b0 >> (8 * lane)) & 0xFF;
            const uint32_t B1 = (uint32_t)(b1 >> (8 * lane)) & 0xFF;
            const uint32_t B2 = (uint32_t)(b2 >> (8 * lane)) & 0xFF;
            const uint32_t B3 = (uint32_t)(b3 >> (8 * lane)) & 0xFF;
            const uint32_t w = spread8(B0) | (spread8(B1) << 1)
                             | (spread8(B2) << 2) | (spread8(B3) << 3);
            lp32[(size_t)chunk * 8 + lane] = w;
        }
    }
}

// ---------------- main reservoir scan: ONE WAVE per sample ----------------
// 512 blocks x 64 threads; lane l owns nodes 4l..4l+3 (state bits v0..v3).
// No __syncthreads / LDS anywhere in the 512-step serial loop:
//   - state mask = 4 ballots (b_k bit l = state of node 4l+k)
//   - lane c computes the permuted T2 byte u_c for chunk c in-register
//   - v_readlane broadcasts u_c (constant lane index in the unrolled loop
//     -> scalar pipe, keeps address math off the VALU critical path)
//   - each lane loads 8B (its 4 node columns) per chunk row: 32 coalesced
//     512B row segments per step (same traffic as the old block version)
//   - packed u16x2 sums in 4-chunk groups (fields <= 51808: no overflow),
//     widened to 4 u32 indices
//   - 4 independent LUT-bit loads finish the step
// Chain/step ~= ballot(60) + T2 issue+latency(~700) + sums(~250) + lp(~600)
// vs the old 2-barrier/2-LDS-round structure at 2625 cy measured.
__global__ __launch_bounds__(64, 1) void reservoir_wave(
    const uint32_t* __restrict__ xp, const uint16_t* __restrict__ T2,
    const uint64_t* __restrict__ lp, const int* __restrict__ input_nodes,
    const uint8_t* __restrict__ init_res, const int* __restrict__ flag,
    const float* __restrict__ rW, const float* __restrict__ rb,
    float* __restrict__ out)
{
    const int m = blockIdx.x;
    const int l = threadIdx.x;          // lane 0..63
    const int stride = (*flag) ? 1 : 4;

    // input-slot assignment for this lane's 4 nodes
    int slot0 = -1, slot1 = -1, slot2 = -1, slot3 = -1;
    for (int i = 0; i < 32; ++i) {
        const int n = input_nodes[i];
        if (n == 4 * l + 0) slot0 = i;
        if (n == 4 * l + 1) slot1 = i;
        if (n == 4 * l + 2) slot2 = i;
        if (n == 4 * l + 3) slot3 = i;
    }
    int v0 = init_res[(size_t)(4 * l + 0) * stride] ? 1 : 0;
    int v1 = init_res[(size_t)(4 * l + 1) * stride] ? 1 : 0;
    int v2 = init_res[(size_t)(4 * l + 2) * stride] ? 1 : 0;
    int v3 = init_res[(size_t)(4 * l + 3) * stride] ? 1 : 0;

    const uint32_t* xrow = xp + m * S_STEPS;
    const uint16_t* T2l  = T2 + 4 * l;          // column base for this lane

    for (int s = 0; s < S_STEPS; ++s) {
        const uint32_t xw = xrow[s];
        if (slot0 >= 0) v0 = (xw >> slot0) & 1;
        if (slot1 >= 0) v1 = (xw >> slot1) & 1;
        if (slot2 >= 0) v2 = (xw >> slot2) & 1;
        if (slot3 >= 0) v3 = (xw >> slot3) & 1;

        const uint64_t b0 = __ballot(v0 != 0);
        const uint64_t b1 = __ballot(v1 != 0);
        const uint64_t b2 = __ballot(v2 != 0);
        const uint64_t b3 = __ballot(v3 != 0);

        // lane c (c<32) holds the permuted byte for chunk c
        const int sh = (2 * l) & 63;
        const uint32_t u = (((uint32_t)(b0 >> sh) & 3u))
                         | (((uint32_t)(b1 >> sh) & 3u) << 2)
                         | (((uint32_t)(b2 >> sh) & 3u) << 4)
                         | (((uint32_t)(b3 >> sh) & 3u) << 6);

        uint32_t i0 = 0, i1 = 0, i2 = 0, i3 = 0;
#pragma unroll
        for (int g = 0; g < 8; ++g) {
            uint32_t lo = 0, hi = 0;
#pragma unroll
            for (int cc = 0; cc < 4; ++cc) {
                const int c = 4 * g + cc;
                const int uc = __builtin_amdgcn_readlane((int)u, c) & 0xFF;
                const uint2 d = *(const uint2*)(T2l + (size_t)((uc << 5) + c) * 256);
                lo += d.x;
                hi += d.y;
            }
            i0 += lo & 0xFFFFu;  i1 += lo >> 16;
            i2 += hi & 0xFFFFu;  i3 += hi >> 16;
        }

        const uint64_t w0 = lp[((size_t)(4 * l + 0) << 12) + (i0 >> 6)];
        const uint64_t w1 = lp[((size_t)(4 * l + 1) << 12) + (i1 >> 6)];
        const uint64_t w2 = lp[((size_t)(4 * l + 2) << 12) + (i2 >> 6)];
        const uint64_t w3 = lp[((size_t)(4 * l + 3) << 12) + (i3 >> 6)];
        v0 = (int)((w0 >> (i0 & 63)) & 1);
        v1 = (int)((w1 >> (i1 & 63)) & 1);
        v2 = (int)((w2 >> (i2 & 63)) & 1);
        v3 = (int)((w3 >> (i3 & 63)) & 1);
    }

    // readout: out[m][o] = b[o] + sum_j v_j * W[o][j]  (wave shuffle reduce)
#pragma unroll
    for (int o = 0; o < OUT_N; ++o) {
        const float* wrow = rW + o * R_NODES + 4 * l;
        float c = 0.f;
        if (v0) c += wrow[0];
        if (v1) c += wrow[1];
        if (v2) c += wrow[2];
        if (v3) c += wrow[3];
#pragma unroll
        for (int off = 32; off > 0; off >>= 1)
            c += __shfl_down(c, off, 64);
        if (l == 0) out[m * OUT_N + o] = c + rb[o];
    }
}

extern "C" void kernel_launch(void* const* d_in, const int* in_sizes, int n_in,
                              void* d_out, int out_size, void* d_ws, size_t ws_size,
                              hipStream_t stream) {
    const uint8_t* x        = (const uint8_t*)d_in[0];   // bool [M,S,D,B]
    const int* input_nodes  = (const int*)d_in[1];       // int32 [32]
    const int* lut          = (const int*)d_in[2];       // int32 [256, 2^18]
    const uint8_t* wres     = (const uint8_t*)d_in[3];   // bool [256,256]
    const int* primes       = (const int*)d_in[4];       // int32 [256]
    const uint8_t* init_res = (const uint8_t*)d_in[5];   // bool [256]
    const float* rW         = (const float*)d_in[6];     // f32 [10,256]
    const float* rb         = (const float*)d_in[7];     // f32 [10]
    float* out              = (float*)d_out;             // f32 [512,10]

    uint8_t* ws = (uint8_t*)d_ws;
    int*      flag = (int*)ws;                                        // 4 B
    uint32_t* xp   = (uint32_t*)(ws + 4096);                          // 1 MB
    uint16_t* T2   = (uint16_t*)(ws + 4096 + 1048576);                // 4 MB
    uint64_t* lp   = (uint64_t*)(ws + 4096 + 1048576 + 4194304);      // 8 MB

    detect_layout<<<1, 256, 0, stream>>>(x, flag);
    pack_x<<<(M_SAMP * S_STEPS * 32) / 256, 256, 0, stream>>>(x, flag, xp);
    build_T2<<<dim3(256, 32), 256, 0, stream>>>(wres, primes, flag, T2);
    pack_lut<<<4096, 256, 0, stream>>>(lut, (uint32_t*)lp);
    reservoir_wave<<<M_SAMP, 64, 0, stream>>>(xp, T2, lp, input_nodes, init_res,
                                              flag, rW, rb, out);
}